// Round 2
// baseline (524.172 us; speedup 1.0000x reference)
//
#include <hip/hip_runtime.h>
#include <hip/hip_bf16.h>
#include <math.h>

typedef __attribute__((ext_vector_type(8))) short bf16x8;
typedef __attribute__((ext_vector_type(4))) float f32x4;

#define NCLS   50000
#define KSUB   3
#define DIM    512
#define NROWSW (NCLS*KSUB)   // 150000
#define BQ     1024

#define SCALEF 30.0f
#define EPSC   1e-7f
#define COSM   0.8775825618903728f
#define SINM   0.4794255386042030f

#define BN     48            // weight rows per LDS tile (lcm(16,3))
#define TW     3             // 16-row MFMA tiles per weight tile
#define NBJ    8             // 16-wide b subtiles per wave (wave = 48r x 128c)
#define NTILES (NROWSW/BN)   // 3125
#define NBLK   256           // persistent blocks, 12-13 tiles each

__device__ __forceinline__ float wave_sum(float v) {
#pragma unroll
  for (int m = 1; m < 64; m <<= 1) v += __shfl_xor(v, m, 64);
  return v;
}

__device__ __forceinline__ short f2bf(float x) {  // RNE f32 -> bf16
  unsigned u = __float_as_uint(x);
  u += 0x7fffu + ((u >> 16) & 1u);
  return (short)(u >> 16);
}

__device__ __forceinline__ float eterm(float v) {
  v = fminf(fmaxf(v, -1.f + EPSC), 1.f - EPSC);
  return __expf(SCALEF * v);
}

// K0: normalize embeddings, store bf16 [1024][512]
__global__ __launch_bounds__(64) void k_norm_e(const float* __restrict__ E,
                                               short* __restrict__ En) {
  const int b = blockIdx.x, l = threadIdx.x;
  const float4* p = reinterpret_cast<const float4*>(E + (size_t)b * DIM + l * 8);
  float4 a = p[0], c = p[1];
  float ss = a.x*a.x + a.y*a.y + a.z*a.z + a.w*a.w
           + c.x*c.x + c.y*c.y + c.z*c.z + c.w*c.w;
  ss = wave_sum(ss);
  float inv = rsqrtf(ss);
  bf16x8 o;
  o[0]=f2bf(a.x*inv); o[1]=f2bf(a.y*inv); o[2]=f2bf(a.z*inv); o[3]=f2bf(a.w*inv);
  o[4]=f2bf(c.x*inv); o[5]=f2bf(c.y*inv); o[6]=f2bf(c.z*inv); o[7]=f2bf(c.w*inv);
  *reinterpret_cast<bf16x8*>(En + (size_t)b * DIM + l * 8) = o;
}

// K-pre: normalize weight rows, store bf16 [150000][512]. 4 rows/block.
__global__ __launch_bounds__(256) void k_prenorm(const float* __restrict__ W,
                                                 short* __restrict__ Wn) {
  const int row = blockIdx.x * 4 + (threadIdx.x >> 6);
  const int l = threadIdx.x & 63;
  const float4* p = reinterpret_cast<const float4*>(W + (size_t)row * DIM + l * 8);
  float4 a = p[0], d = p[1];
  float ss = a.x*a.x + a.y*a.y + a.z*a.z + a.w*a.w
           + d.x*d.x + d.y*d.y + d.z*d.z + d.w*d.w;
  ss = wave_sum(ss);
  float inv = rsqrtf(ss);
  bf16x8 o;
  o[0]=f2bf(a.x*inv); o[1]=f2bf(a.y*inv); o[2]=f2bf(a.z*inv); o[3]=f2bf(a.w*inv);
  o[4]=f2bf(d.x*inv); o[5]=f2bf(d.y*inv); o[6]=f2bf(d.z*inv); o[7]=f2bf(d.w*inv);
  *reinterpret_cast<bf16x8*>(Wn + (size_t)row * DIM + l * 8) = o;
}

// K2: exact f32 target-class cosine + margin terms (1 wave per batch row)
__global__ __launch_bounds__(64) void k_target(const float* __restrict__ E,
                                               const int* __restrict__ lab,
                                               const float* __restrict__ W,
                                               float* __restrict__ delta,
                                               float* __restrict__ tl) {
  const int b = blockIdx.x, l = threadIdx.x;
  const float4* pe = reinterpret_cast<const float4*>(E + (size_t)b * DIM + l * 8);
  float4 e0 = pe[0], e1 = pe[1];
  float es = e0.x*e0.x + e0.y*e0.y + e0.z*e0.z + e0.w*e0.w
           + e1.x*e1.x + e1.y*e1.y + e1.z*e1.z + e1.w*e1.w;
  es = wave_sum(es);
  const int L = lab[b];
  float mx = -2.f;
#pragma unroll
  for (int k = 0; k < KSUB; ++k) {
    const float4* pw = reinterpret_cast<const float4*>(W + (size_t)(L * KSUB + k) * DIM + l * 8);
    float4 w0 = pw[0], w1 = pw[1];
    float ds = e0.x*w0.x + e0.y*w0.y + e0.z*w0.z + e0.w*w0.w
             + e1.x*w1.x + e1.y*w1.y + e1.z*w1.z + e1.w*w1.w;
    float ws = w0.x*w0.x + w0.y*w0.y + w0.z*w0.z + w0.w*w0.w
             + w1.x*w1.x + w1.y*w1.y + w1.z*w1.z + w1.w*w1.w;
    ds = wave_sum(ds);
    ws = wave_sum(ws);
    float ck = ds * rsqrtf(es * ws);
    mx = fmaxf(mx, ck);
  }
  if (l == 0) {
    float cc = fminf(fmaxf(mx, -1.f + EPSC), 1.f - EPSC);
    float sn = sqrtf(fmaxf(1.f - cc * cc, 0.f));
    float mg = cc * COSM - sn * SINM;           // cos(arccos(cc)+m)
    delta[b] = __expf(SCALEF * mg) - __expf(SCALEF * cc);
    tl[b]    = SCALEF * mg;
  }
}

// stage one 48-row bf16 tile into LDS buffer via global_load_lds.
// LDS layout: [48][64] 16B-chunks, chunk slot holds data chunk (slot ^ (row&7)).
// Wave wv stages row i*8+wv per pass: per-lane global src is the inverse-swizzled
// chunk; LDS dest is linear (wave-uniform base + lane*16) per HW semantics.
__device__ __forceinline__ void stage_tile(const short* __restrict__ Wn,
                                           short* lbuf, int tile, int wv, int lane) {
#pragma unroll
  for (int i = 0; i < BN / 8; ++i) {
    const int row = i * 8 + wv;
    const int d = lane ^ (row & 7);
    const short* src = Wn + ((size_t)tile * BN + row) * DIM + d * 8;
    __builtin_amdgcn_global_load_lds(
        (const __attribute__((address_space(1))) unsigned int*)src,
        (__attribute__((address_space(3))) unsigned int*)(lbuf + row * DIM),
        16, 0, 0);
  }
}

// K1: main GEMM + fused max/exp/sum epilogue.
// Block: 48 rows x 1024 cols per tile, dbuf LDS, 12-13 tiles per block.
__global__ __launch_bounds__(512) void k_main(const short* __restrict__ Wn,
                                              const short* __restrict__ En,
                                              float* __restrict__ Zp) {
  extern __shared__ __align__(16) short wlds[];   // 2 x 48KB
  const int tid  = threadIdx.x;
  const int lane = tid & 63;
  const int wv   = tid >> 6;
  const int g    = lane >> 4;
  const int c    = lane & 15;

  float zreg[NBJ];
#pragma unroll
  for (int j = 0; j < NBJ; ++j) zreg[j] = 0.f;

  int tile = blockIdx.x;
  stage_tile(Wn, wlds, tile, wv, lane);
  __syncthreads();
  int cur = 0;

  for (; tile < NTILES; tile += NBLK) {
    const int nxt = tile + NBLK;
    if (nxt < NTILES) stage_tile(Wn, wlds + (cur ^ 1) * (BN * DIM), nxt, wv, lane);

    const bf16x8* wl8 = reinterpret_cast<const bf16x8*>(wlds + cur * (BN * DIM));

    f32x4 acc[TW][NBJ];
#pragma unroll
    for (int t = 0; t < TW; ++t)
#pragma unroll
      for (int j = 0; j < NBJ; ++j) acc[t][j] = (f32x4){0.f, 0.f, 0.f, 0.f};

#pragma unroll 4
    for (int ks = 0; ks < DIM / 32; ++ks) {
      bf16x8 bfr[NBJ];
#pragma unroll
      for (int j = 0; j < NBJ; ++j)
        bfr[j] = *reinterpret_cast<const bf16x8*>(
            En + (size_t)(wv * 128 + j * 16 + c) * DIM + ks * 32 + g * 8);
      const int sc = (ks * 4 + g) ^ (c & 7);
#pragma unroll
      for (int t = 0; t < TW; ++t) {
        bf16x8 af = wl8[(t * 16 + c) * 64 + sc];
#pragma unroll
        for (int j = 0; j < NBJ; ++j)
          acc[t][j] = __builtin_amdgcn_mfma_f32_16x16x32_bf16(af, bfr[j], acc[t][j], 0, 0, 0);
      }
    }

    // epilogue: max over sub-center triples, exp, per-col partial sums
#pragma unroll
    for (int j = 0; j < NBJ; ++j) {
      float zc = 0.f;
#pragma unroll
      for (int t = 0; t < TW; ++t) {
        float s0, s1;
        if (t + 1 < TW) {
          s0 = (g == 0) ? acc[t + 1][j][0] : acc[t][j][0];
          s1 = (g == 0) ? acc[t + 1][j][1] : acc[t][j][1];
        } else {
          s0 = (g == 0) ? -2.f : acc[t][j][0];
          s1 = (g == 0) ? -2.f : acc[t][j][1];
        }
        float e0 = __shfl(s0, (lane + 16) & 63, 64);
        float e1 = __shfl(s1, (lane + 16) & 63, 64);
        const int m = (4 * t + g) % 3;
        float a0 = acc[t][j][0], a1 = acc[t][j][1], a2 = acc[t][j][2], a3 = acc[t][j][3];
        if (m == 0)      zc += eterm(fmaxf(fmaxf(a0, a1), a2)) + eterm(fmaxf(fmaxf(a3, e0), e1));
        else if (m == 1) zc += eterm(fmaxf(fmaxf(a2, a3), e0));
        else             zc += eterm(fmaxf(fmaxf(a1, a2), a3));
      }
      zc += __shfl_xor(zc, 16, 64);
      zc += __shfl_xor(zc, 32, 64);
      zreg[j] += zc;
    }

    __syncthreads();   // stage(cur^1) complete + all waves done with cur
    cur ^= 1;
  }

  if (g == 0) {
#pragma unroll
    for (int j = 0; j < NBJ; ++j)
      Zp[(size_t)blockIdx.x * BQ + wv * 128 + j * 16 + c] = zreg[j];
  }
}

// K3: Z[b] = sum of partials; per-row loss; block partial sums
__global__ __launch_bounds__(256) void k_reduce(const float* __restrict__ Zp,
                                                const float* __restrict__ delta,
                                                const float* __restrict__ tl,
                                                float* __restrict__ part) {
  const int b = blockIdx.x * 256 + threadIdx.x;
  float z = 0.f;
  for (int nb = 0; nb < NBLK; ++nb) z += Zp[(size_t)nb * BQ + b];
  float lossb = logf(z + delta[b]) - tl[b];
  __shared__ float sm[256];
  sm[threadIdx.x] = lossb;
  __syncthreads();
#pragma unroll
  for (int s = 128; s > 0; s >>= 1) {
    if (threadIdx.x < s) sm[threadIdx.x] += sm[threadIdx.x + s];
    __syncthreads();
  }
  if (threadIdx.x == 0) part[blockIdx.x] = sm[0];
}

__global__ void k_final(const float* __restrict__ part, float* __restrict__ out) {
  out[0] = (part[0] + part[1] + part[2] + part[3]) * (1.0f / BQ);
}

extern "C" void kernel_launch(void* const* d_in, const int* in_sizes, int n_in,
                              void* d_out, int out_size, void* d_ws, size_t ws_size,
                              hipStream_t stream) {
  const float* E  = (const float*)d_in[0];
  const int* lab  = (const int*)d_in[1];
  const float* W  = (const float*)d_in[2];

  char* ws = (char*)d_ws;
  short* En    = (short*)ws;                                    // 1 MB
  short* Wn    = (short*)(ws + (size_t)BQ * DIM * 2);           // 153.6 MB
  char*  after = ws + (size_t)BQ * DIM * 2 + (size_t)NROWSW * DIM * 2;
  float* Zp    = (float*)after;                                 // 256*1024*4 = 1 MB
  float* delta = (float*)(after + (size_t)NBLK * BQ * 4);
  float* tl    = delta + BQ;
  float* part  = tl + BQ;

  hipFuncSetAttribute(reinterpret_cast<const void*>(&k_main),
                      hipFuncAttributeMaxDynamicSharedMemorySize, 2 * BN * DIM * 2);

  hipLaunchKernelGGL(k_prenorm, dim3(NROWSW / 4), dim3(256), 0, stream, W, Wn);
  hipLaunchKernelGGL(k_norm_e,  dim3(BQ),         dim3(64),  0, stream, E, En);
  hipLaunchKernelGGL(k_target,  dim3(BQ),         dim3(64),  0, stream, E, lab, W, delta, tl);
  hipLaunchKernelGGL(k_main,    dim3(NBLK),       dim3(512), 2 * BN * DIM * 2, stream, Wn, En, Zp);
  hipLaunchKernelGGL(k_reduce,  dim3(4),          dim3(256), 0, stream, Zp, delta, tl, part);
  hipLaunchKernelGGL(k_final,   dim3(1),          dim3(1),   0, stream, part, (float*)d_out);
}

// Round 3
// 482.847 us; speedup vs baseline: 1.0856x; 1.0856x over previous
//
#include <hip/hip_runtime.h>
#include <math.h>

typedef __attribute__((ext_vector_type(4))) float f32x4;

#define NCLS   50000
#define KSUB   3
#define DIM    512            // elements; fp8 row = 512 bytes
#define NROWSW (NCLS*KSUB)    // 150000
#define BQ     1024

#define SCALEF 30.0f
#define EPSC   1e-7f
#define COSM   0.8775825618903728f
#define SINM   0.4794255386042030f

#define BN     48             // weight rows per LDS tile (lcm(16,3))
#define TW     3              // 16-row MFMA tiles
#define NBJ    4              // 16-wide b subtiles per wave PER HALF
#define NHALF  2              // 2 x 512 cols processed sequentially (halves acc VGPRs)
#define NTILES (NROWSW/BN)    // 3125
#define NBLK   512            // 2 blocks/CU resident
#define TILEB  (BN*DIM)       // 24576 B per LDS buffer (fp8)

__device__ __forceinline__ float wave_sum(float v) {
#pragma unroll
  for (int m = 1; m < 64; m <<= 1) v += __shfl_xor(v, m, 64);
  return v;
}

__device__ __forceinline__ unsigned pack4_fp8(float a, float b, float c, float d) {
  int v = 0;
  v = __builtin_amdgcn_cvt_pk_fp8_f32(a, b, v, false);  // bytes 0,1
  v = __builtin_amdgcn_cvt_pk_fp8_f32(c, d, v, true);   // bytes 2,3
  return (unsigned)v;
}

__device__ __forceinline__ float eterm(float v) {
  v = fminf(fmaxf(v, -1.f + EPSC), 1.f - EPSC);
  return __expf(SCALEF * v);
}

// K0: normalize embeddings, store fp8 e4m3 [1024][512]
__global__ __launch_bounds__(64) void k_norm_e(const float* __restrict__ E,
                                               unsigned char* __restrict__ En8) {
  const int b = blockIdx.x, l = threadIdx.x;
  const float4* p = reinterpret_cast<const float4*>(E + (size_t)b * DIM + l * 8);
  float4 a = p[0], c = p[1];
  float ss = a.x*a.x + a.y*a.y + a.z*a.z + a.w*a.w
           + c.x*c.x + c.y*c.y + c.z*c.z + c.w*c.w;
  ss = wave_sum(ss);
  float inv = rsqrtf(ss);
  uint2 o;
  o.x = pack4_fp8(a.x*inv, a.y*inv, a.z*inv, a.w*inv);
  o.y = pack4_fp8(c.x*inv, c.y*inv, c.z*inv, c.w*inv);
  *reinterpret_cast<uint2*>(En8 + (size_t)b * DIM + l * 8) = o;
}

// K-pre: normalize weight rows, store fp8 e4m3 [150000][512]
__global__ __launch_bounds__(256) void k_prenorm(const float* __restrict__ W,
                                                 unsigned char* __restrict__ Wn8) {
  const int row = blockIdx.x * 4 + (threadIdx.x >> 6);
  const int l = threadIdx.x & 63;
  const float4* p = reinterpret_cast<const float4*>(W + (size_t)row * DIM + l * 8);
  float4 a = p[0], d = p[1];
  float ss = a.x*a.x + a.y*a.y + a.z*a.z + a.w*a.w
           + d.x*d.x + d.y*d.y + d.z*d.z + d.w*d.w;
  ss = wave_sum(ss);
  float inv = rsqrtf(ss);
  uint2 o;
  o.x = pack4_fp8(a.x*inv, a.y*inv, a.z*inv, a.w*inv);
  o.y = pack4_fp8(d.x*inv, d.y*inv, d.z*inv, d.w*inv);
  *reinterpret_cast<uint2*>(Wn8 + (size_t)row * DIM + l * 8) = o;
}

// K2: exact f32 target-class cosine + margin terms (unchanged, verified)
__global__ __launch_bounds__(64) void k_target(const float* __restrict__ E,
                                               const int* __restrict__ lab,
                                               const float* __restrict__ W,
                                               float* __restrict__ delta,
                                               float* __restrict__ tl) {
  const int b = blockIdx.x, l = threadIdx.x;
  const float4* pe = reinterpret_cast<const float4*>(E + (size_t)b * DIM + l * 8);
  float4 e0 = pe[0], e1 = pe[1];
  float es = e0.x*e0.x + e0.y*e0.y + e0.z*e0.z + e0.w*e0.w
           + e1.x*e1.x + e1.y*e1.y + e1.z*e1.z + e1.w*e1.w;
  es = wave_sum(es);
  const int L = lab[b];
  float mx = -2.f;
#pragma unroll
  for (int k = 0; k < KSUB; ++k) {
    const float4* pw = reinterpret_cast<const float4*>(W + (size_t)(L * KSUB + k) * DIM + l * 8);
    float4 w0 = pw[0], w1 = pw[1];
    float ds = e0.x*w0.x + e0.y*w0.y + e0.z*w0.z + e0.w*w0.w
             + e1.x*w1.x + e1.y*w1.y + e1.z*w1.z + e1.w*w1.w;
    float ws = w0.x*w0.x + w0.y*w0.y + w0.z*w0.z + w0.w*w0.w
             + w1.x*w1.x + w1.y*w1.y + w1.z*w1.z + w1.w*w1.w;
    ds = wave_sum(ds);
    ws = wave_sum(ws);
    float ck = ds * rsqrtf(es * ws);
    mx = fmaxf(mx, ck);
  }
  if (l == 0) {
    float cc = fminf(fmaxf(mx, -1.f + EPSC), 1.f - EPSC);
    float sn = sqrtf(fmaxf(1.f - cc * cc, 0.f));
    float mg = cc * COSM - sn * SINM;           // cos(arccos(cc)+m)
    delta[b] = __expf(SCALEF * mg) - __expf(SCALEF * cc);
    tl[b]    = SCALEF * mg;
  }
}

// stage one 48-row fp8 tile (24 KB). Each gload issue = 1 KB = 2 rows.
// LDS 16B-chunk slot s of row r holds global chunk s ^ (r&7) (read-side swizzle).
__device__ __forceinline__ void stage_tile(const unsigned char* __restrict__ Wn8,
                                           unsigned char* lbuf, int tile, int wv, int lane) {
#pragma unroll
  for (int i = 0; i < 3; ++i) {
    const int row0 = wv * 6 + 2 * i;
    const int row  = row0 + (lane >> 5);
    const int sc   = (lane & 31) ^ (row & 7);
    const unsigned char* src = Wn8 + ((size_t)tile * BN + row) * DIM + sc * 16;
    __builtin_amdgcn_global_load_lds(
        (const __attribute__((address_space(1))) unsigned int*)src,
        (__attribute__((address_space(3))) unsigned int*)(lbuf + row0 * DIM),
        16, 0, 0);
  }
}

// K1: fp8 GEMM + fused max/exp/sum epilogue. 48-row tiles, dbuf 48KB LDS,
// N=1024 in two 512-col halves (acc pressure), 2 blocks/CU.
__global__ __launch_bounds__(512, 4) void k_main(const unsigned char* __restrict__ Wn8,
                                                 const unsigned char* __restrict__ En8,
                                                 float* __restrict__ Zp) {
  __shared__ __align__(16) unsigned char wlds[2 * TILEB];
  const int tid  = threadIdx.x;
  const int lane = tid & 63;
  const int wv   = tid >> 6;
  const int g    = lane >> 4;
  const int c    = lane & 15;

  float zreg[NHALF][NBJ];
#pragma unroll
  for (int h = 0; h < NHALF; ++h)
#pragma unroll
    for (int j = 0; j < NBJ; ++j) zreg[h][j] = 0.f;

  int tile = blockIdx.x;
  stage_tile(Wn8, wlds, tile, wv, lane);
  __syncthreads();
  int cur = 0;

  for (; tile < NTILES; tile += NBLK) {
    const int nxt = tile + NBLK;
    if (nxt < NTILES) stage_tile(Wn8, wlds + (cur ^ 1) * TILEB, nxt, wv, lane);
    const unsigned char* lbuf = wlds + cur * TILEB;

#pragma unroll
    for (int h = 0; h < NHALF; ++h) {
      const int jb = h * 512 + wv * 64;
      f32x4 acc[TW][NBJ];
#pragma unroll
      for (int t = 0; t < TW; ++t)
#pragma unroll
        for (int j = 0; j < NBJ; ++j) acc[t][j] = (f32x4){0.f, 0.f, 0.f, 0.f};

#pragma unroll 4
      for (int ks = 0; ks < DIM / 32; ++ks) {
        long bfr[NBJ];
#pragma unroll
        for (int j = 0; j < NBJ; ++j)
          bfr[j] = *reinterpret_cast<const long*>(
              En8 + (size_t)(jb + j * 16 + c) * DIM + ks * 32 + g * 8);
#pragma unroll
        for (int t = 0; t < TW; ++t) {
          const int row = t * 16 + c;
          long af = *reinterpret_cast<const long*>(
              lbuf + row * DIM + (((ks * 2 + (g >> 1)) ^ (row & 7)) << 4) + (g & 1) * 8);
#pragma unroll
          for (int j = 0; j < NBJ; ++j)
            acc[t][j] = __builtin_amdgcn_mfma_f32_16x16x32_fp8_fp8(af, bfr[j], acc[t][j], 0, 0, 0);
        }
      }

      // epilogue: max over sub-center triples (verified logic), exp, per-col sums
#pragma unroll
      for (int j = 0; j < NBJ; ++j) {
        float zc = 0.f;
#pragma unroll
        for (int t = 0; t < TW; ++t) {
          float s0, s1;
          if (t + 1 < TW) {
            s0 = (g == 0) ? acc[t + 1][j][0] : acc[t][j][0];
            s1 = (g == 0) ? acc[t + 1][j][1] : acc[t][j][1];
          } else {
            s0 = (g == 0) ? -2.f : acc[t][j][0];
            s1 = (g == 0) ? -2.f : acc[t][j][1];
          }
          float e0 = __shfl(s0, (lane + 16) & 63, 64);
          float e1 = __shfl(s1, (lane + 16) & 63, 64);
          const int m = (4 * t + g) % 3;
          float a0 = acc[t][j][0], a1 = acc[t][j][1], a2 = acc[t][j][2], a3 = acc[t][j][3];
          if (m == 0)      zc += eterm(fmaxf(fmaxf(a0, a1), a2)) + eterm(fmaxf(fmaxf(a3, e0), e1));
          else if (m == 1) zc += eterm(fmaxf(fmaxf(a2, a3), e0));
          else             zc += eterm(fmaxf(fmaxf(a1, a2), a3));
        }
        zc += __shfl_xor(zc, 16, 64);
        zc += __shfl_xor(zc, 32, 64);
        zreg[h][j] += zc;
      }
    }

    __syncthreads();   // stage(cur^1) drained + all waves done with cur
    cur ^= 1;
  }

  if (g == 0) {
#pragma unroll
    for (int h = 0; h < NHALF; ++h)
#pragma unroll
      for (int j = 0; j < NBJ; ++j)
        Zp[(size_t)blockIdx.x * BQ + h * 512 + wv * 64 + j * 16 + c] = zreg[h][j];
  }
}

// K3: Z[b] = sum of partials; per-row loss; block partial sums
__global__ __launch_bounds__(256) void k_reduce(const float* __restrict__ Zp,
                                                const float* __restrict__ delta,
                                                const float* __restrict__ tl,
                                                float* __restrict__ part) {
  const int b = blockIdx.x * 256 + threadIdx.x;
  float z = 0.f;
  for (int nb = 0; nb < NBLK; ++nb) z += Zp[(size_t)nb * BQ + b];
  float lossb = logf(z + delta[b]) - tl[b];
  __shared__ float sm[256];
  sm[threadIdx.x] = lossb;
  __syncthreads();
#pragma unroll
  for (int s = 128; s > 0; s >>= 1) {
    if (threadIdx.x < s) sm[threadIdx.x] += sm[threadIdx.x + s];
    __syncthreads();
  }
  if (threadIdx.x == 0) part[blockIdx.x] = sm[0];
}

__global__ void k_final(const float* __restrict__ part, float* __restrict__ out) {
  out[0] = (part[0] + part[1] + part[2] + part[3]) * (1.0f / BQ);
}

extern "C" void kernel_launch(void* const* d_in, const int* in_sizes, int n_in,
                              void* d_out, int out_size, void* d_ws, size_t ws_size,
                              hipStream_t stream) {
  const float* E  = (const float*)d_in[0];
  const int* lab  = (const int*)d_in[1];
  const float* W  = (const float*)d_in[2];

  char* ws = (char*)d_ws;
  unsigned char* En8 = (unsigned char*)ws;                          // 512 KB
  unsigned char* Wn8 = (unsigned char*)(ws + (size_t)BQ * DIM);     // 76.8 MB
  char* after = ws + (size_t)BQ * DIM + (size_t)NROWSW * DIM;
  float* Zp    = (float*)after;                                     // 512*1024*4 = 2 MB
  float* delta = Zp + (size_t)NBLK * BQ;
  float* tl    = delta + BQ;
  float* part  = tl + BQ;

  hipLaunchKernelGGL(k_prenorm, dim3(NROWSW / 4), dim3(256), 0, stream, W, Wn8);
  hipLaunchKernelGGL(k_norm_e,  dim3(BQ),         dim3(64),  0, stream, E, En8);
  hipLaunchKernelGGL(k_target,  dim3(BQ),         dim3(64),  0, stream, E, lab, W, delta, tl);
  hipLaunchKernelGGL(k_main,    dim3(NBLK),       dim3(512), 0, stream, Wn8, En8, Zp);
  hipLaunchKernelGGL(k_reduce,  dim3(4),          dim3(256), 0, stream, Zp, delta, tl, part);
  hipLaunchKernelGGL(k_final,   dim3(1),          dim3(1),   0, stream, part, (float*)d_out);
}